// Round 5
// baseline (1892.738 us; speedup 1.0000x reference)
//
#include <hip/hip_runtime.h>
#include <math.h>

namespace {

constexpr int TNZ = 8, TNY = 512, TNX = 512, TNM = 4, TM = 128;
constexpr int PITCH = 130;                 // float2 pitch of LDS transpose buffer
constexpr float F0 = 1.0f / (TM * 0.2f);   // fftfreq step 1/(M*dr)
constexpr float PK = -3.14159265358979323846f * 0.025f * 10.0f;  // -pi*lambda*dz
constexpr float INV_N2 = 1.0f / (TM * TM);
constexpr float EPSV = 1e-10f;

__device__ __forceinline__ float2 cmul(float2 a, float2 b) {
  return make_float2(a.x * b.x - a.y * b.y, a.x * b.y + a.y * b.x);
}
__device__ __forceinline__ float2 cmulc(float2 a, float2 b) {  // a * conj(b)
  return make_float2(a.x * b.x + a.y * b.y, a.y * b.x - a.x * b.y);
}
// Cross-lane exchange within lane-quads via DPP quad_perm (VALU-pipe, no LDS).
// XOR1 -> quad_perm [1,0,3,2] = 0xB1 ; XOR2 -> [2,3,0,1] = 0x4E.
template <int CTRL>
__device__ __forceinline__ float dppf(float v) {
  return __int_as_float(
      __builtin_amdgcn_mov_dpp(__float_as_int(v), CTRL, 0xF, 0xF, true));
}
template <int M>
__device__ __forceinline__ float2 shq(float2 v) {
  constexpr int CTRL = (M == 1) ? 0xB1 : 0x4E;
  return make_float2(dppf<CTRL>(v.x), dppf<CTRL>(v.y));
}
// Column swizzle: fold segment bits (5-6) of the column index into bits 0-1.
// Both transpose phases hit the b64 bank floor (uniform 4 lanes/bank-pair).
__device__ __forceinline__ int swc(int col) { return col ^ ((col & 0x60) >> 5); }
__device__ __forceinline__ int rev7(int n) {
  return ((n & 1) << 6) | ((n & 2) << 4) | ((n & 4) << 2) | (n & 8) |
         ((n & 16) >> 2) | ((n & 32) >> 4) | ((n & 64) >> 6);
}

// ---- local (in-thread) radix-2 stages over 32 elements ----
// twd[m] = exp(-2*pi*i*m/128), m < 64
template <int H>
__device__ __forceinline__ void dif_local(float2 (&X)[32], const float2* twd) {
#pragma unroll
  for (int m = 0; m < H; ++m) {
    float2 W = twd[m * (64 / H)];
#pragma unroll
    for (int b = 0; b < 32; b += 2 * H) {
      const int j = b + m;
      float2 A = X[j], B = X[j + H];
      X[j] = make_float2(A.x + B.x, A.y + B.y);
      float2 d = make_float2(A.x - B.x, A.y - B.y);
      X[j + H] = cmul(d, W);
    }
  }
}
template <int H>
__device__ __forceinline__ void dit_local(float2 (&X)[32], const float2* twd) {
#pragma unroll
  for (int m = 0; m < H; ++m) {
    float2 W = twd[m * (64 / H)];
#pragma unroll
    for (int b = 0; b < 32; b += 2 * H) {
      const int j = b + m;
      float2 A = X[j];
      float2 B = cmulc(X[j + H], W);
      X[j] = make_float2(A.x + B.x, A.y + B.y);
      X[j + H] = make_float2(A.x - B.x, A.y - B.y);
    }
  }
}

// Forward DIF FFT-128. Thread segment s (0..3) owns n = 32*s + j.
// Natural order in, bit-reversed positions out.
__device__ __forceinline__ void dif128(float2 (&X)[32], const float2* twd,
                                       const float2* twdp, int s) {
  const bool b2 = (s & 2) != 0, b1 = (s & 1) != 0;
  // stage h=64, partner lane ^2 ; W = W128^{32*(s&1)+j} (padded table)
#pragma unroll
  for (int j = 0; j < 32; ++j) {
    float2 o = shq<2>(X[j]);
    float2 W = twdp[(s & 1) * 33 + j];
    float2 sum = make_float2(X[j].x + o.x, X[j].y + o.y);
    float2 dif = make_float2(o.x - X[j].x, o.y - X[j].y);
    float2 pr = cmul(dif, W);
    X[j] = b2 ? pr : sum;
  }
  // stage h=32, partner ^1 ; W = W64^j = twd[2j] (wave-uniform)
#pragma unroll
  for (int j = 0; j < 32; ++j) {
    float2 o = shq<1>(X[j]);
    float2 W = twd[2 * j];
    float2 sum = make_float2(X[j].x + o.x, X[j].y + o.y);
    float2 dif = make_float2(o.x - X[j].x, o.y - X[j].y);
    float2 pr = cmul(dif, W);
    X[j] = b1 ? pr : sum;
  }
  dif_local<16>(X, twd);
  dif_local<8>(X, twd);
  dif_local<4>(X, twd);
  dif_local<2>(X, twd);
#pragma unroll
  for (int b = 0; b < 32; b += 2) {  // h=1, W=1
    float2 A = X[b], B = X[b + 1];
    X[b] = make_float2(A.x + B.x, A.y + B.y);
    X[b + 1] = make_float2(A.x - B.x, A.y - B.y);
  }
}

// Inverse (DIT) FFT-128: exact inverse network (bitrev in, natural out, unscaled)
__device__ __forceinline__ void dit128(float2 (&X)[32], const float2* twd,
                                       const float2* twdp, int s) {
  const bool b2 = (s & 2) != 0, b1 = (s & 1) != 0;
#pragma unroll
  for (int b = 0; b < 32; b += 2) {  // h=1
    float2 A = X[b], B = X[b + 1];
    X[b] = make_float2(A.x + B.x, A.y + B.y);
    X[b + 1] = make_float2(A.x - B.x, A.y - B.y);
  }
  dit_local<2>(X, twd);
  dit_local<4>(X, twd);
  dit_local<8>(X, twd);
  dit_local<16>(X, twd);
  // cross h=32, partner ^1 : W = twd[2j]
  {
    const float sg = b1 ? -1.0f : 1.0f;
#pragma unroll
    for (int j = 0; j < 32; ++j) {
      float2 o = shq<1>(X[j]);
      float2 W = twd[2 * j];
      float2 vin = b1 ? X[j] : o;  // upper element value
      float2 u = b1 ? o : X[j];    // lower element value
      float2 B = cmulc(vin, W);
      X[j] = make_float2(fmaf(sg, B.x, u.x), fmaf(sg, B.y, u.y));
    }
  }
  // cross h=64, partner ^2 : W = twdp[(s&1)*33+j]
  {
    const float sg = b2 ? -1.0f : 1.0f;
#pragma unroll
    for (int j = 0; j < 32; ++j) {
      float2 o = shq<2>(X[j]);
      float2 W = twdp[(s & 1) * 33 + j];
      float2 vin = b2 ? X[j] : o;
      float2 u = b2 ? o : X[j];
      float2 B = cmulc(vin, W);
      X[j] = make_float2(fmaf(sg, B.x, u.x), fmaf(sg, B.y, u.y));
    }
  }
}

__global__ __launch_bounds__(512, 1)
void msp_fwd(const float* __restrict__ V, const float* __restrict__ Pre,
             const float* __restrict__ Pim, const int* __restrict__ pos,
             float* __restrict__ out) {
  __shared__ float2 fld[TM * PITCH];  // 133,120 B transpose buffer
  __shared__ float2 twd[64];
  __shared__ float2 twdp[2 * 33];     // W128^{32p+j} at [p*33+j] (padded)
  __shared__ float2 hyt[4 * 33];      // hy for storage idx n=32s+j at [s*33+j]

  const int t = threadIdx.x;
  const int k = blockIdx.x;
  const int s = t & 3;    // segment: owns x = 32*s + j
  const int rc = t >> 2;  // row (row passes) / col (col passes), 0..127

  if (t < 64) {
    float ang = -6.28318530717958647692f * (float)t / 128.0f;
    float2 w = make_float2(cosf(ang), sinf(ang));
    twd[t] = w;
    twdp[(t >> 5) * 33 + (t & 31)] = w;  // W128^t
  }
  if (t < 128) {
    const int ky = rev7(t);
    const int iy = ky - ((ky & 64) ? 128 : 0);
    const float fy = iy * F0;
    const float ph = PK * fy * fy;
    hyt[(t >> 5) * 33 + (t & 31)] = make_float2(cosf(ph), sinf(ph));
  }
  __syncthreads();

  const int p0 = pos[2 * k];
  const int p1 = pos[2 * k + 1];

  // per-thread H x-factor: kx = bitrev7(rc); fold ifft 1/N^2 into it
  const int kx = rev7(rc);
  const int ixf = kx - ((kx & 64) ? 128 : 0);
  const float fx2 = (ixf * F0) * (ixf * F0);
  const float phx = PK * fx2;
  const float2 hxv = make_float2(cosf(phx) * INV_N2, sinf(phx) * INV_N2);

  float acc[32];
#pragma unroll
  for (int j = 0; j < 32; ++j) acc[j] = 0.0f;

  float2 X[32];

  for (int m = 0; m < TNM; ++m) {
    // load probe mode m (row ownership: row rc, cols 32s..32s+31)
    {
      const float* pr = Pre + ((m * TM + rc) * TM + 32 * s);
      const float* pi = Pim + ((m * TM + rc) * TM + 32 * s);
#pragma unroll
      for (int q = 0; q < 8; ++q) {
        float4 a = reinterpret_cast<const float4*>(pr)[q];
        float4 b = reinterpret_cast<const float4*>(pi)[q];
        X[4 * q + 0] = make_float2(a.x, b.x);
        X[4 * q + 1] = make_float2(a.y, b.y);
        X[4 * q + 2] = make_float2(a.z, b.z);
        X[4 * q + 3] = make_float2(a.w, b.w);
      }
    }

    for (int z = 0; z < TNZ; ++z) {
      // multiply by T = exp(i*V) at patch (p0+rc, p1 + 32s + j)
      {
        const float* vb = V + ((z * TNY + (p0 + rc)) * TNX + p1 + 32 * s);
#pragma unroll
        for (int j = 0; j < 32; ++j) {
          float v = vb[j];
          float sv, cv;
          __sincosf(v, &sv, &cv);
          X[j] = cmul(X[j], make_float2(cv, sv));
        }
      }
      dif128(X, twd, twdp, s);  // rows
      // transpose rows -> cols (swizzled b64)
      __syncthreads();
#pragma unroll
      for (int j = 0; j < 32; ++j) fld[rc * PITCH + swc(32 * s + j)] = X[j];
      __syncthreads();
#pragma unroll
      for (int j = 0; j < 32; ++j) X[j] = fld[(32 * s + j) * PITCH + swc(rc)];

      dif128(X, twd, twdp, s);  // cols

      if (z == TNZ - 1) break;  // last slice: no propagation

      // H multiply at (ky=rev7(32s+j), kx=rev7(rc)), separable; INV_N2 in hxv
#pragma unroll
      for (int j = 0; j < 32; ++j) {
        float2 hy = hyt[s * 33 + j];
        X[j] = cmul(cmul(X[j], hy), hxv);
      }

      dit128(X, twd, twdp, s);  // cols inverse
      // transpose cols -> rows (swizzled b64)
      __syncthreads();
#pragma unroll
      for (int j = 0; j < 32; ++j) fld[(32 * s + j) * PITCH + swc(rc)] = X[j];
      __syncthreads();
#pragma unroll
      for (int j = 0; j < 32; ++j) X[j] = fld[rc * PITCH + swc(32 * s + j)];
      dit128(X, twd, twdp, s);  // rows inverse
    }

    // accumulate |psi_f|^2 (unnormalized)
#pragma unroll
    for (int j = 0; j < 32; ++j)
      acc[j] = fmaf(X[j].x, X[j].x, fmaf(X[j].y, X[j].y, acc[j]));
  }

  // un-bit-reverse via LDS, then coalesced global write of amp
  __syncthreads();
  float* fldf = reinterpret_cast<float*>(fld);
  const int r2s = ((s & 1) << 1) | (s >> 1);  // rev2(s)
#pragma unroll
  for (int j = 0; j < 32; ++j) {
    const int r5 = ((j & 1) << 4) | ((j & 2) << 2) | (j & 4) | ((j & 8) >> 2) |
                   ((j & 16) >> 4);
    const int ky = (r5 << 2) | r2s;   // rev7(32s+j)
    fldf[ky * PITCH + kx] = acc[j];
  }
  __syncthreads();
  float* ob = out + k * (TM * TM);
#pragma unroll
  for (int i = 0; i < 32; ++i) {
    const int idx = t + 512 * i;
    const int yy = idx >> 7, xx = idx & 127;
    const float a = fldf[yy * PITCH + xx];
    ob[idx] = sqrtf(EPSV + a * INV_N2);  // ortho: 1/128 per fft2 -> 1/16384 on |.|^2
  }
}

}  // namespace

extern "C" void kernel_launch(void* const* d_in, const int* in_sizes, int n_in,
                              void* d_out, int out_size, void* d_ws, size_t ws_size,
                              hipStream_t stream) {
  (void)in_sizes; (void)n_in; (void)out_size; (void)d_ws; (void)ws_size;
  const float* V = (const float*)d_in[0];
  const float* Pre = (const float*)d_in[1];
  const float* Pim = (const float*)d_in[2];
  const int* pos = (const int*)d_in[3];
  float* out = (float*)d_out;
  msp_fwd<<<dim3(256), dim3(512), 0, stream>>>(V, Pre, Pim, pos, out);
}

// Round 6
// 1298.932 us; speedup vs baseline: 1.4572x; 1.4572x over previous
//
#include <hip/hip_runtime.h>
#include <math.h>

namespace {

constexpr int TNZ = 8, TNY = 512, TNX = 512, TM = 128;
constexpr int PITCH = 130;                 // float2 pitch of LDS transpose buffer
constexpr float F0 = 1.0f / (TM * 0.2f);   // fftfreq step 1/(M*dr)
constexpr float PK = -3.14159265358979323846f * 0.025f * 10.0f;  // -pi*lambda*dz
constexpr float INV_N2 = 1.0f / (TM * TM);
constexpr float EPSV = 1e-10f;

__device__ __forceinline__ float2 cmul(float2 a, float2 b) {
  return make_float2(a.x * b.x - a.y * b.y, a.x * b.y + a.y * b.x);
}
__device__ __forceinline__ float2 cmulc(float2 a, float2 b) {  // a * conj(b)
  return make_float2(a.x * b.x + a.y * b.y, a.y * b.x - a.x * b.y);
}
__device__ __forceinline__ float2 shxor(float2 v, int m) {
  return make_float2(__shfl_xor(v.x, m, 64), __shfl_xor(v.y, m, 64));
}
// Column swizzle: fold segment bits (5-6) of the column index into bits 0-1.
// Both transpose phases hit the b64 bank floor (uniform 4 lanes/bank-pair).
__device__ __forceinline__ int swc(int col) { return col ^ ((col & 0x60) >> 5); }
__device__ __forceinline__ int rev7(int n) {
  return ((n & 1) << 6) | ((n & 2) << 4) | ((n & 4) << 2) | (n & 8) |
         ((n & 16) >> 2) | ((n & 32) >> 4) | ((n & 64) >> 6);
}

// ---- local (in-thread) radix-2 stages over 32 elements ----
// twd[m] = exp(-2*pi*i*m/128), m < 64
template <int H>
__device__ __forceinline__ void dif_local(float2 (&X)[32], const float2* twd) {
#pragma unroll
  for (int m = 0; m < H; ++m) {
    float2 W = twd[m * (64 / H)];
#pragma unroll
    for (int b = 0; b < 32; b += 2 * H) {
      const int j = b + m;
      float2 A = X[j], B = X[j + H];
      X[j] = make_float2(A.x + B.x, A.y + B.y);
      float2 d = make_float2(A.x - B.x, A.y - B.y);
      X[j + H] = cmul(d, W);
    }
  }
}
template <int H>
__device__ __forceinline__ void dit_local(float2 (&X)[32], const float2* twd) {
#pragma unroll
  for (int m = 0; m < H; ++m) {
    float2 W = twd[m * (64 / H)];
#pragma unroll
    for (int b = 0; b < 32; b += 2 * H) {
      const int j = b + m;
      float2 A = X[j];
      float2 B = cmulc(X[j + H], W);
      X[j] = make_float2(A.x + B.x, A.y + B.y);
      X[j + H] = make_float2(A.x - B.x, A.y - B.y);
    }
  }
}

// Forward DIF FFT-128. Thread segment s (0..3) owns n = 32*s + j.
// Natural order in, bit-reversed positions out.
__device__ __forceinline__ void dif128(float2 (&X)[32], const float2* twd, int s) {
  const bool b2 = (s & 2) != 0, b1 = (s & 1) != 0;
  // stage h=64, partner lane ^2 ; W = twd[32*(s&1)+j] = twd[j] * (b1 ? -i : 1)
#pragma unroll
  for (int j = 0; j < 32; ++j) {
    float2 o = shxor(X[j], 2);
    float2 tw = twd[j];
    float2 W = b1 ? make_float2(tw.y, -tw.x) : tw;
    float2 sum = make_float2(X[j].x + o.x, X[j].y + o.y);
    float2 dif = make_float2(o.x - X[j].x, o.y - X[j].y);
    float2 pr = cmul(dif, W);
    X[j] = b2 ? pr : sum;
  }
  // stage h=32, partner ^1 ; W = W64^j = twd[2j] (wave-uniform)
#pragma unroll
  for (int j = 0; j < 32; ++j) {
    float2 o = shxor(X[j], 1);
    float2 W = twd[2 * j];
    float2 sum = make_float2(X[j].x + o.x, X[j].y + o.y);
    float2 dif = make_float2(o.x - X[j].x, o.y - X[j].y);
    float2 pr = cmul(dif, W);
    X[j] = b1 ? pr : sum;
  }
  dif_local<16>(X, twd);
  dif_local<8>(X, twd);
  dif_local<4>(X, twd);
  dif_local<2>(X, twd);
#pragma unroll
  for (int b = 0; b < 32; b += 2) {  // h=1, W=1
    float2 A = X[b], B = X[b + 1];
    X[b] = make_float2(A.x + B.x, A.y + B.y);
    X[b + 1] = make_float2(A.x - B.x, A.y - B.y);
  }
}

// Inverse (DIT) FFT-128: exact inverse network (bitrev in, natural out, unscaled)
__device__ __forceinline__ void dit128(float2 (&X)[32], const float2* twd, int s) {
  const bool b2 = (s & 2) != 0, b1 = (s & 1) != 0;
#pragma unroll
  for (int b = 0; b < 32; b += 2) {  // h=1
    float2 A = X[b], B = X[b + 1];
    X[b] = make_float2(A.x + B.x, A.y + B.y);
    X[b + 1] = make_float2(A.x - B.x, A.y - B.y);
  }
  dit_local<2>(X, twd);
  dit_local<4>(X, twd);
  dit_local<8>(X, twd);
  dit_local<16>(X, twd);
  // cross h=32, partner ^1 : W = twd[2j], conj applied
  {
    const float sg = b1 ? -1.0f : 1.0f;
#pragma unroll
    for (int j = 0; j < 32; ++j) {
      float2 o = shxor(X[j], 1);
      float2 W = twd[2 * j];
      float2 vin = b1 ? X[j] : o;  // upper element value
      float2 u = b1 ? o : X[j];    // lower element value
      float2 B = cmulc(vin, W);
      X[j] = make_float2(fmaf(sg, B.x, u.x), fmaf(sg, B.y, u.y));
    }
  }
  // cross h=64, partner ^2 : cW = conj(twd[j] * (b1 ? -i : 1))
  {
    const float sg = b2 ? -1.0f : 1.0f;
#pragma unroll
    for (int j = 0; j < 32; ++j) {
      float2 o = shxor(X[j], 2);
      float2 tw = twd[j];
      float2 cW = b1 ? make_float2(tw.y, tw.x) : make_float2(tw.x, -tw.y);
      float2 vin = b2 ? X[j] : o;
      float2 u = b2 ? o : X[j];
      float2 B = cmul(vin, cW);
      X[j] = make_float2(fmaf(sg, B.x, u.x), fmaf(sg, B.y, u.y));
    }
  }
}

// One block = one (k, mode). Accumulates |psi_f|^2 into out via atomicAdd.
__global__ __launch_bounds__(512, 1)
void msp_mode(const float* __restrict__ V, const float* __restrict__ Pre,
              const float* __restrict__ Pim, const int* __restrict__ pos,
              float* __restrict__ out) {
  __shared__ float2 fld[TM * PITCH];  // 133,120 B transpose buffer
  __shared__ float2 twd[64];
  __shared__ float2 hyt[4 * 33];  // hy for storage idx n=32s+j at [s*33+j]

  const int t = threadIdx.x;
  const int k = blockIdx.x >> 2;
  const int m = blockIdx.x & 3;
  const int s = t & 3;    // segment: owns x = 32*s + j
  const int rc = t >> 2;  // row (row passes) / col (col passes), 0..127

  if (t < 64) {
    float ang = -6.28318530717958647692f * (float)t / 128.0f;
    twd[t] = make_float2(cosf(ang), sinf(ang));
  }
  if (t < 128) {
    const int ky = rev7(t);
    const int iy = ky - ((ky & 64) ? 128 : 0);
    const float fy = iy * F0;
    const float ph = PK * fy * fy;
    hyt[(t >> 5) * 33 + (t & 31)] = make_float2(cosf(ph), sinf(ph));
  }
  __syncthreads();

  const int p0 = pos[2 * k];
  const int p1 = pos[2 * k + 1];

  // per-thread H x-factor: kx = bitrev7(rc); fold ifft 1/N^2 into it
  const int kx = rev7(rc);
  const int ixf = kx - ((kx & 64) ? 128 : 0);
  const float fx2 = (ixf * F0) * (ixf * F0);
  const float phx = PK * fx2;
  const float2 hxv = make_float2(cosf(phx) * INV_N2, sinf(phx) * INV_N2);

  float2 X[32];

  // load probe mode m (row ownership: row rc, cols 32s..32s+31)
  {
    const float* pr = Pre + ((m * TM + rc) * TM + 32 * s);
    const float* pi = Pim + ((m * TM + rc) * TM + 32 * s);
#pragma unroll
    for (int q = 0; q < 8; ++q) {
      float4 a = reinterpret_cast<const float4*>(pr)[q];
      float4 b = reinterpret_cast<const float4*>(pi)[q];
      X[4 * q + 0] = make_float2(a.x, b.x);
      X[4 * q + 1] = make_float2(a.y, b.y);
      X[4 * q + 2] = make_float2(a.z, b.z);
      X[4 * q + 3] = make_float2(a.w, b.w);
    }
  }

  for (int z = 0; z < TNZ; ++z) {
    // multiply by T = exp(i*V) at patch (p0+rc, p1 + 32s + j)
    {
      const float* vb = V + ((z * TNY + (p0 + rc)) * TNX + p1 + 32 * s);
#pragma unroll
      for (int j = 0; j < 32; ++j) {
        float v = vb[j];
        float sv, cv;
        __sincosf(v, &sv, &cv);
        X[j] = cmul(X[j], make_float2(cv, sv));
      }
    }
    dif128(X, twd, s);  // rows
    // transpose rows -> cols (swizzled b64)
    __syncthreads();
#pragma unroll
    for (int j = 0; j < 32; ++j) fld[rc * PITCH + swc(32 * s + j)] = X[j];
    __syncthreads();
#pragma unroll
    for (int j = 0; j < 32; ++j) X[j] = fld[(32 * s + j) * PITCH + swc(rc)];

    dif128(X, twd, s);  // cols

    if (z == TNZ - 1) break;  // last slice: no propagation

    // H multiply at (ky=rev7(32s+j), kx=rev7(rc)), separable; INV_N2 in hxv
#pragma unroll
    for (int j = 0; j < 32; ++j) {
      float2 hy = hyt[s * 33 + j];
      X[j] = cmul(cmul(X[j], hy), hxv);
    }

    dit128(X, twd, s);  // cols inverse
    // transpose cols -> rows (swizzled b64)
    __syncthreads();
#pragma unroll
    for (int j = 0; j < 32; ++j) fld[(32 * s + j) * PITCH + swc(rc)] = X[j];
    __syncthreads();
#pragma unroll
    for (int j = 0; j < 32; ++j) X[j] = fld[rc * PITCH + swc(32 * s + j)];
    dit128(X, twd, s);  // rows inverse
  }

  // un-bit-reverse |X|^2 via LDS, then coalesced global atomic accumulate
  __syncthreads();
  float* fldf = reinterpret_cast<float*>(fld);
  const int r2s = ((s & 1) << 1) | (s >> 1);  // rev2(s)
#pragma unroll
  for (int j = 0; j < 32; ++j) {
    const int r5 = ((j & 1) << 4) | ((j & 2) << 2) | (j & 4) | ((j & 8) >> 2) |
                   ((j & 16) >> 4);
    const int ky = (r5 << 2) | r2s;  // rev7(32s+j)
    fldf[ky * PITCH + kx] = fmaf(X[j].x, X[j].x, X[j].y * X[j].y);
  }
  __syncthreads();
  float* ob = out + k * (TM * TM);
#pragma unroll
  for (int i = 0; i < 32; ++i) {
    const int idx = t + 512 * i;
    const int yy = idx >> 7, xx = idx & 127;
    atomicAdd(&ob[idx], fldf[yy * PITCH + xx]);
  }
}

__global__ __launch_bounds__(256) void zero_k(float4* __restrict__ p, int n4) {
  const int i = blockIdx.x * 256 + threadIdx.x;
  if (i < n4) p[i] = make_float4(0.f, 0.f, 0.f, 0.f);
}

__global__ __launch_bounds__(256) void sqrt_k(float* __restrict__ p, int n) {
  const int i = blockIdx.x * 256 + threadIdx.x;
  if (i < n) p[i] = sqrtf(EPSV + p[i] * INV_N2);  // ortho: 1/N^2 on |.|^2
}

}  // namespace

extern "C" void kernel_launch(void* const* d_in, const int* in_sizes, int n_in,
                              void* d_out, int out_size, void* d_ws, size_t ws_size,
                              hipStream_t stream) {
  (void)in_sizes; (void)n_in; (void)d_ws; (void)ws_size;
  const float* V = (const float*)d_in[0];
  const float* Pre = (const float*)d_in[1];
  const float* Pim = (const float*)d_in[2];
  const int* pos = (const int*)d_in[3];
  float* out = (float*)d_out;
  const int n = out_size;        // 256*128*128
  const int n4 = n >> 2;
  zero_k<<<dim3((n4 + 255) / 256), dim3(256), 0, stream>>>((float4*)out, n4);
  msp_mode<<<dim3(1024), dim3(512), 0, stream>>>(V, Pre, Pim, pos, out);
  sqrt_k<<<dim3((n + 255) / 256), dim3(256), 0, stream>>>(out, n);
}